// Round 1
// baseline (115.687 us; speedup 1.0000x reference)
//
#include <hip/hip_runtime.h>

#define H_IN   181
#define W_IN   360
#define NLAT   361
#define NLON   720
#define CIN    16
#define COUT   16
#define KSZ    3
#define NNZ    8192
#define MAXB   64                 // max nonzeros per (lat,parity) bucket (mean ~11.3)
#define XPLANE (H_IN * W_IN)      // 65160 floats per input channel

// ---------------------------------------------------------------------------
// Fully fused, ZERO-workspace DISCO transpose conv.
//
// Block = (ho, parity). Each entry (k,hin,p,v) with p-parity matching this
// block contributes v * x[c][hin][y] to out lons L = p + 2*y (L parity == p
// parity). Thread t owns lon = 2t+pe, i.e. exactly one y per entry.
//
// Instead of materializing the channel-mixed xw in global scratch (which
// forces the harness's 2x 256MiB workspace re-poison fills = ~89us of the
// 99us iteration), each thread accumulates the k-split channel gather
//   G[k][c] += v * x[c][hin][y]          (48 regs, ~11 entries)
// and applies the 16x16x3 weight mix once in the epilogue:
//   out[co] = bias[co] + sum_{k,c} G[k][c] * w[co][c][k]
// Weights are wave-uniform compile-time-indexed -> scalar (s_load) feeds.
// ---------------------------------------------------------------------------
__global__ __launch_bounds__(384) void fused_disco_kernel(
    const float* __restrict__ x,        // [CIN][H_IN][W_IN]
    const float* __restrict__ w,        // [COUT][CIN][KSZ]
    const float* __restrict__ bias,     // [COUT]
    const int*   __restrict__ ker_idx,  // [NNZ]
    const int*   __restrict__ row_idx,  // [NNZ]
    const int*   __restrict__ col_idx,  // [NNZ]
    const float* __restrict__ vals,     // [NNZ]
    float* __restrict__ out)            // [COUT][NLAT][NLON]
{
    const int ho  = blockIdx.x >> 1;
    const int pe  = blockIdx.x & 1;     // longitude parity owned by this block
    const int tid = threadIdx.x;

    __shared__ int   s_cnt;
    __shared__ int   s_xrow[MAXB];      // row_idx * W_IN  (x row offset)
    __shared__ int   s_pk[MAXB];        // p | (k << 12)
    __shared__ float s_v[MAXB];

    if (tid == 0) s_cnt = 0;
    __syncthreads();

    // ---- bucket scan: entries with out-lat == ho and p-parity == pe ----
    for (int n = tid; n < NNZ; n += 384) {
        const int c  = col_idx[n];
        const int hi = c / NLON;
        const int p  = c - hi * NLON;
        if (hi == ho && (p & 1) == pe) {
            const int slot = atomicAdd(&s_cnt, 1);
            if (slot < MAXB) {
                s_xrow[slot] = row_idx[n] * W_IN;
                s_pk[slot]   = p | (ker_idx[n] << 12);
                s_v[slot]    = vals[n];
            }
        }
    }
    __syncthreads();
    const int cnt = (s_cnt < MAXB) ? s_cnt : MAXB;

    if (tid >= 360) return;
    const int lon = 2 * tid + pe;       // this thread's output longitude

    // ---- per-thread k-split channel gather ----
    float g0[CIN], g1[CIN], g2[CIN];
#pragma unroll
    for (int c = 0; c < CIN; ++c) { g0[c] = 0.f; g1[c] = 0.f; g2[c] = 0.f; }

    for (int e = 0; e < cnt; ++e) {
        // entry fields are identical across the wave -> hoist to SGPRs
        const int   pk = __builtin_amdgcn_readfirstlane(s_pk[e]);
        const int   xr = __builtin_amdgcn_readfirstlane(s_xrow[e]);
        const float v  = __uint_as_float(
                           __builtin_amdgcn_readfirstlane(__float_as_uint(s_v[e])));
        const int p = pk & 0xfff;
        const int k = pk >> 12;

        int d = lon - p;                // even by parity construction
        if (d < 0) d += NLON;
        const int y = d >> 1;           // input longitude in [0,360)

        const float* xp = x + xr + y;   // + c*XPLANE per channel
        float xv[CIN];
#pragma unroll
        for (int c = 0; c < CIN; ++c) xv[c] = xp[c * XPLANE];

        if (k == 0) {
#pragma unroll
            for (int c = 0; c < CIN; ++c) g0[c] += v * xv[c];
        } else if (k == 1) {
#pragma unroll
            for (int c = 0; c < CIN; ++c) g1[c] += v * xv[c];
        } else {
#pragma unroll
            for (int c = 0; c < CIN; ++c) g2[c] += v * xv[c];
        }
    }

    // ---- epilogue: 16x(16x3) weight mix, weights are uniform -> s_loads ----
#pragma unroll
    for (int co = 0; co < COUT; ++co) {
        float s = bias[co];
#pragma unroll
        for (int c = 0; c < CIN; ++c) {
            const int wb = (co * CIN + c) * KSZ;
            s += g0[c] * w[wb + 0];
            s += g1[c] * w[wb + 1];
            s += g2[c] * w[wb + 2];
        }
        out[((size_t)co * NLAT + ho) * NLON + lon] = s;
    }
}

// ---------------------------------------------------------------------------
extern "C" void kernel_launch(void* const* d_in, const int* in_sizes, int n_in,
                              void* d_out, int out_size, void* d_ws, size_t ws_size,
                              hipStream_t stream) {
    const float* x       = (const float*)d_in[0];
    const float* weight  = (const float*)d_in[1];
    const float* bias    = (const float*)d_in[2];
    const int*   ker_idx = (const int*)d_in[3];
    const int*   row_idx = (const int*)d_in[4];
    const int*   col_idx = (const int*)d_in[5];
    const float* vals    = (const float*)d_in[6];
    float* out = (float*)d_out;

    (void)d_ws; (void)ws_size;   // deliberately workspace-free

    fused_disco_kernel<<<NLAT * 2, 384, 0, stream>>>(
        x, weight, bias, ker_idx, row_idx, col_idx, vals, out);
}